// Round 2
// 246.430 us; speedup vs baseline: 1.0535x; 1.0535x over previous
//
#include <hip/hip_runtime.h>

#define DD 64
#define BSH 8            // bucket = dst >> 8 (256 dsts per bucket)
#define NB_MAX 512       // supports n <= 131072
#define SCAP 4096        // staging slots per bucket (mean 3196, +16 sigma)
#define BIN_CH 4096      // edges per bin-kernel block

typedef __attribute__((ext_vector_type(8))) short bf16x8;
typedef __attribute__((ext_vector_type(4))) float f32x4;
union Frag { bf16x8 v; uint32_t d[4]; };

__device__ __forceinline__ float bf_lo(uint32_t d) { return __uint_as_float(d << 16); }
__device__ __forceinline__ float bf_hi(uint32_t d) { return __uint_as_float(d & 0xffff0000u); }
__device__ __forceinline__ float bf2f(uint32_t h) { return __uint_as_float(h << 16); }
__device__ __forceinline__ uint32_t f2bf(float f) {  // round-to-nearest-even
    uint32_t u = __float_as_uint(f);
    u += 0x7fffu + ((u >> 16) & 1u);
    return u >> 16;
}

// ====== K1: bin edges into dst-buckets (fixed-stride staging, LDS-aggregated) ======
__global__ __launch_bounds__(256) void bin_kernel(const int* __restrict__ src,
                                                  const int* __restrict__ dst,
                                                  int* __restrict__ bcnt,
                                                  uint32_t* __restrict__ staging,
                                                  int E, int NB) {
    __shared__ uint32_t cnt[NB_MAX];
    __shared__ uint32_t resv[NB_MAX];
    __shared__ uint16_t rk[BIN_CH];
    int tid = threadIdx.x;
    int base = blockIdx.x * BIN_CH;
    for (int b = tid; b < NB; b += 256) cnt[b] = 0;
    __syncthreads();
    for (int k = tid; k < BIN_CH; k += 256) {
        int g = base + k;
        if (g < E) {
            int b = dst[g] >> BSH;
            rk[k] = (uint16_t)atomicAdd(&cnt[b], 1u);
        }
    }
    __syncthreads();
    for (int b = tid; b < NB; b += 256) {
        uint32_t c = cnt[b];
        resv[b] = c ? (uint32_t)atomicAdd(&bcnt[b], (int)c) : 0u;
    }
    __syncthreads();
    for (int k = tid; k < BIN_CH; k += 256) {
        int g = base + k;
        if (g < E) {
            int s = src[g], d = dst[g];
            int b = d >> BSH;
            uint32_t pos = resv[b] + rk[k];
            if (pos < SCAP)  // statistically impossible overflow guard
                staging[(size_t)b * SCAP + pos] = ((uint32_t)s << BSH) | (uint32_t)(d & ((1 << BSH) - 1));
        }
    }
}

// ====== K3: per-bucket sort -> rowptr, inv, CSR srcs (coalesced out) ======
__global__ __launch_bounds__(256) void sort_kernel(const int* __restrict__ bcnt,
                                                   const uint32_t* __restrict__ staging,
                                                   int* __restrict__ rowptr,
                                                   float* __restrict__ inv,
                                                   uint32_t* __restrict__ srcs,
                                                   int n, int E, int NB) {
    __shared__ uint32_t raw[SCAP];
    __shared__ uint32_t sorted[SCAP];
    __shared__ int scnt[1 << BSH];
    __shared__ int soff[1 << BSH];
    __shared__ int lcur[1 << BSH];
    __shared__ int red[256];
    int tid = threadIdx.x;
    int b = blockIdx.x;
    int base = b << BSH;
    int nd = min(1 << BSH, n - base);
    int cb = min(bcnt[b], SCAP);

    // bucket global base = prefix sum of bcnt[0..b)
    int part = 0;
    for (int j = tid; j < b; j += 256) part += bcnt[j];
    red[tid] = part;
    __syncthreads();
    for (int o = 128; o > 0; o >>= 1) {
        if (tid < o) red[tid] += red[tid + o];
        __syncthreads();
    }
    int bbase = red[0];

    // load records, histogram by local dst
    scnt[tid] = 0;
    if (tid < ((1 << BSH) - 256)) {}  // (1<<BSH)==256: scnt fully covered
    __syncthreads();
    for (int k = tid; k < cb; k += 256) {
        uint32_t w = staging[(size_t)b * SCAP + k];
        raw[k] = w;
        atomicAdd(&scnt[w & ((1 << BSH) - 1)], 1);
    }
    __syncthreads();
    // exclusive scan of 256 counters (Hillis-Steele)
    int v = scnt[tid];
    red[tid] = v;
    __syncthreads();
    for (int o = 1; o < 256; o <<= 1) {
        int t = (tid >= o) ? red[tid - o] : 0;
        __syncthreads();
        red[tid] += t;
        __syncthreads();
    }
    soff[tid] = red[tid] - v;
    lcur[tid] = red[tid] - v;
    if (tid < nd) {
        rowptr[base + tid] = bbase + soff[tid];
        inv[base + tid] = rsqrtf((float)v + 1.0f);
    }
    if (b == NB - 1 && tid == 0) rowptr[n] = E;
    __syncthreads();
    // place into sorted order
    for (int k = tid; k < cb; k += 256) {
        uint32_t w = raw[k];
        int p = atomicAdd(&lcur[w & ((1 << BSH) - 1)], 1);
        sorted[p] = w >> BSH;
    }
    __syncthreads();
    for (int k = tid; k < cb; k += 256) srcs[bbase + k] = sorted[k];  // coalesced
}

// ====== MFMA GEMM: [n,64] @ [64,64] -> bf16 rows PRE-SCALED by inv[row]. ======
// 16x16x32 bf16, split-bf16 = fp32-exact. Pre-scaling removes the per-edge
// inv[src] gather in agg: sum_j inv[s]*xw[s]*inv[i] = inv[i]*sum_j(inv[s]*xw[s]).
template <int XBF>
__global__ __launch_bounds__(256) void gemm64_mfma(const void* __restrict__ Xv,
                                                   const float* __restrict__ W,
                                                   const float* __restrict__ inv,
                                                   uint16_t* __restrict__ Y, int n) {
    __shared__ float Ws[DD * DD];
    int tid = threadIdx.x;
    for (int i = tid; i < DD * DD; i += 256) Ws[i] = W[i];
    __syncthreads();
    int lane = tid & 63, quad = lane >> 4, l16 = lane & 15;

    Frag bhi[4][2], blo[4][2];
#pragma unroll
    for (int t = 0; t < 4; ++t)
#pragma unroll
        for (int c = 0; c < 2; ++c) {
            int col = t * 16 + l16;
            int kb = c * 32 + quad * 8;
#pragma unroll
            for (int i = 0; i < 4; ++i) {
                float w0 = Ws[(kb + 2 * i) * DD + col];
                float w1 = Ws[(kb + 2 * i + 1) * DD + col];
                uint32_t h0 = f2bf(w0), h1 = f2bf(w1);
                uint32_t l0 = f2bf(w0 - bf2f(h0)), l1 = f2bf(w1 - bf2f(h1));
                bhi[t][c].d[i] = h0 | (h1 << 16);
                blo[t][c].d[i] = l0 | (l1 << 16);
            }
        }

    int ngroups = (n + 15) >> 4;
    int nwaves = gridDim.x * 4;
    int wid = blockIdx.x * 4 + (tid >> 6);
    for (int g = wid; g < ngroups; g += nwaves) {
        int rb = g << 4;
        int row = min(rb + l16, n - 1);
        f32x4 acc[4];
#pragma unroll
        for (int t = 0; t < 4; ++t) acc[t] = (f32x4){0.f, 0.f, 0.f, 0.f};
#pragma unroll
        for (int c = 0; c < 2; ++c) {
            Frag ahi, alo;
            if constexpr (XBF == 0) {
                const float* xr = (const float*)Xv + (size_t)row * DD + c * 32 + quad * 8;
                float4 x0 = *(const float4*)xr;
                float4 x1 = *(const float4*)(xr + 4);
                float f[8] = {x0.x, x0.y, x0.z, x0.w, x1.x, x1.y, x1.z, x1.w};
#pragma unroll
                for (int i = 0; i < 4; ++i) {
                    uint32_t h0 = f2bf(f[2 * i]), h1 = f2bf(f[2 * i + 1]);
                    ahi.d[i] = h0 | (h1 << 16);
                    alo.d[i] = f2bf(f[2 * i] - bf2f(h0)) | (f2bf(f[2 * i + 1] - bf2f(h1)) << 16);
                }
            } else {
                const int4* xr = (const int4*)((const uint32_t*)Xv + (size_t)row * 32 + c * 16 + quad * 4);
                int4 a = *xr;
                ahi.d[0] = a.x; ahi.d[1] = a.y; ahi.d[2] = a.z; ahi.d[3] = a.w;
            }
#pragma unroll
            for (int t = 0; t < 4; ++t) {
                acc[t] = __builtin_amdgcn_mfma_f32_16x16x32_bf16(ahi.v, bhi[t][c].v, acc[t], 0, 0, 0);
                acc[t] = __builtin_amdgcn_mfma_f32_16x16x32_bf16(ahi.v, blo[t][c].v, acc[t], 0, 0, 0);
                if constexpr (XBF == 0)
                    acc[t] = __builtin_amdgcn_mfma_f32_16x16x32_bf16(alo.v, bhi[t][c].v, acc[t], 0, 0, 0);
            }
        }
#pragma unroll
        for (int r = 0; r < 4; ++r) {
            int ro = rb + quad * 4 + r;
            if (ro < n) {
                float sc = inv[ro];
#pragma unroll
                for (int t = 0; t < 4; ++t)
                    Y[(size_t)ro * DD + t * 16 + l16] = (uint16_t)f2bf(acc[t][r] * sc);
            }
        }
    }
}

// ====== fused aggregation: one wave per node, 8 edges per step (rows pre-scaled) ======
// Group g (8 lanes) owns edge stream jstart+g, +8, ...; lane m loads row dwords 4m..4m+3 (16 B).
// No per-edge coef: rows carry inv[src]; whole sum (incl. self row) is scaled by inv[dst] once.
// src prefetch 3 ahead; row prefetch 2 ahead. 16 rows in flight per wave.
template <int MODE>
__global__ __launch_bounds__(256) void agg_kernel(const int* __restrict__ rowptr,
                                                  const uint32_t* __restrict__ srcs,
                                                  const float* __restrict__ inv,
                                                  const uint32_t* __restrict__ XWb,  // [n][32] dwords
                                                  const float* __restrict__ b,
                                                  void* __restrict__ OUTv, int n) {
    int gid = blockIdx.x * 256 + threadIdx.x;
    int i = gid >> 6, lane = gid & 63;
    if (i >= n) return;
    int g = lane >> 3, m = lane & 7;

    float a[8];
#pragma unroll
    for (int k = 0; k < 8; ++k) a[k] = 0.f;
    if (g == 0) {  // self-loop: row i is pre-scaled by inv[i]; final *iv gives inv[i]^2
        int4 d = *(const int4*)(XWb + (size_t)i * 32 + 4 * m);
        a[0] = bf_lo((uint32_t)d.x); a[1] = bf_hi((uint32_t)d.x);
        a[2] = bf_lo((uint32_t)d.y); a[3] = bf_hi((uint32_t)d.y);
        a[4] = bf_lo((uint32_t)d.z); a[5] = bf_hi((uint32_t)d.z);
        a[6] = bf_lo((uint32_t)d.w); a[7] = bf_hi((uint32_t)d.w);
    }

    int jstart = rowptr[i], jend = rowptr[i + 1];  // wave-uniform
    if (jstart < jend) {
        int last = jend - 1;
        int jq = jstart + g;  // this group's stream: jq, jq+8, ...
        uint32_t s0 = srcs[min(jq, last)];
        uint32_t s1 = srcs[min(jq + 8, last)];
        uint32_t s2 = srcs[min(jq + 16, last)];
        int4 d0 = *(const int4*)(XWb + (size_t)s0 * 32 + 4 * m);
        int4 d1 = *(const int4*)(XWb + (size_t)s1 * 32 + 4 * m);
        for (int j = jq; j < jend; j += 8) {
            uint32_t s3 = srcs[min(j + 24, last)];                    // src prefetch (3 ahead)
            int4 d2 = *(const int4*)(XWb + (size_t)s2 * 32 + 4 * m);  // row prefetch (2 ahead)
            a[0] += bf_lo((uint32_t)d0.x); a[1] += bf_hi((uint32_t)d0.x);
            a[2] += bf_lo((uint32_t)d0.y); a[3] += bf_hi((uint32_t)d0.y);
            a[4] += bf_lo((uint32_t)d0.z); a[5] += bf_hi((uint32_t)d0.z);
            a[6] += bf_lo((uint32_t)d0.w); a[7] += bf_hi((uint32_t)d0.w);
            s2 = s3;
            d0 = d1; d1 = d2;
        }
    }

    // combine 8 groups: lanes {m, m+8, ..., m+56} hold partials for features 8m..8m+7
#pragma unroll
    for (int k = 0; k < 8; ++k) {
        a[k] += __shfl_xor(a[k], 8, 64);
        a[k] += __shfl_xor(a[k], 16, 64);
        a[k] += __shfl_xor(a[k], 32, 64);
    }

    float iv = inv[i];  // wave-uniform
    float4 bb0 = *(const float4*)(b + 8 * m);
    float4 bb1 = *(const float4*)(b + 8 * m + 4);
    float f0 = fmaf(a[0], iv, bb0.x), f1 = fmaf(a[1], iv, bb0.y);
    float f2 = fmaf(a[2], iv, bb0.z), f3 = fmaf(a[3], iv, bb0.w);
    float f4 = fmaf(a[4], iv, bb1.x), f5 = fmaf(a[5], iv, bb1.y);
    float f6 = fmaf(a[6], iv, bb1.z), f7 = fmaf(a[7], iv, bb1.w);

    if (MODE == 0) {
        if (g == 0) {
            int4 d;
            d.x = (int)((f2bf(fmaxf(f1, 0.f)) << 16) | f2bf(fmaxf(f0, 0.f)));
            d.y = (int)((f2bf(fmaxf(f3, 0.f)) << 16) | f2bf(fmaxf(f2, 0.f)));
            d.z = (int)((f2bf(fmaxf(f5, 0.f)) << 16) | f2bf(fmaxf(f4, 0.f)));
            d.w = (int)((f2bf(fmaxf(f7, 0.f)) << 16) | f2bf(fmaxf(f6, 0.f)));
            *(int4*)((uint32_t*)OUTv + (size_t)i * 32 + 4 * m) = d;
        }
    } else {
        float mx = fmaxf(fmaxf(fmaxf(f0, f1), fmaxf(f2, f3)),
                         fmaxf(fmaxf(f4, f5), fmaxf(f6, f7)));
#pragma unroll
        for (int o = 4; o > 0; o >>= 1) mx = fmaxf(mx, __shfl_xor(mx, o, 64));
        float e = __expf(f0 - mx) + __expf(f1 - mx) + __expf(f2 - mx) + __expf(f3 - mx)
                + __expf(f4 - mx) + __expf(f5 - mx) + __expf(f6 - mx) + __expf(f7 - mx);
#pragma unroll
        for (int o = 4; o > 0; o >>= 1) e += __shfl_xor(e, o, 64);
        float ls = __logf(e);
        if (g == 0) {
            float4 r0 = make_float4(f0 - mx - ls, f1 - mx - ls, f2 - mx - ls, f3 - mx - ls);
            float4 r1 = make_float4(f4 - mx - ls, f5 - mx - ls, f6 - mx - ls, f7 - mx - ls);
            *(float4*)((float*)OUTv + (size_t)i * DD + 8 * m) = r0;
            *(float4*)((float*)OUTv + (size_t)i * DD + 8 * m + 4) = r1;
        }
    }
}

extern "C" void kernel_launch(void* const* d_in, const int* in_sizes, int n_in,
                              void* d_out, int out_size, void* d_ws, size_t ws_size,
                              hipStream_t stream) {
    const float* x  = (const float*)d_in[0];
    const int*   ei = (const int*)d_in[1];
    const float* W1 = (const float*)d_in[2];
    const float* b1 = (const float*)d_in[3];
    const float* W2 = (const float*)d_in[4];
    const float* b2 = (const float*)d_in[5];
    float* out = (float*)d_out;

    const int n = in_sizes[0] / DD;
    const int E = in_sizes[1] / 2;
    const int* src = ei;
    const int* dst = ei + E;
    const int NB = (n + (1 << BSH) - 1) >> BSH;  // 391 for n=100k

    // workspace layout (int units)
    size_t off = 0;
    int* base = (int*)d_ws;
    int* bcnt = base + off; off += NB_MAX;
    uint32_t* staging = (uint32_t*)(base + off); off += (size_t)NB_MAX * SCAP;
    uint32_t* srcs = (uint32_t*)(base + off); off += E;
    int* rowptr = base + off; off += (size_t)n + 1;
    float* inv  = (float*)(base + off); off += n;
    uint32_t* XWb = (uint32_t*)(base + off); off += (size_t)n * 32;  // bf16 [n][64]
    uint32_t* hb  = (uint32_t*)(base + off); off += (size_t)n * 32;  // bf16 [n][64]

    hipMemsetAsync(bcnt, 0, NB_MAX * sizeof(int), stream);
    bin_kernel<<<(E + BIN_CH - 1) / BIN_CH, 256, 0, stream>>>(src, dst, bcnt, staging, E, NB);
    sort_kernel<<<NB, 256, 0, stream>>>(bcnt, staging, rowptr, inv, srcs, n, E, NB);

    // layer 1 (gemm pre-scales rows by inv[row]; needs sort_kernel's inv -> same stream, ordered)
    gemm64_mfma<0><<<1024, 256, 0, stream>>>(x, W1, inv, (uint16_t*)XWb, n);
    agg_kernel<0><<<(n * DD + 255) / 256, 256, 0, stream>>>(rowptr, srcs, inv, XWb, b1, hb, n);

    // layer 2
    gemm64_mfma<1><<<1024, 256, 0, stream>>>(hb, W2, inv, (uint16_t*)XWb, n);
    agg_kernel<1><<<(n * DD + 255) / 256, 256, 0, stream>>>(rowptr, srcs, inv, XWb, b2, out, n);
}

// Round 3
// 241.422 us; speedup vs baseline: 1.0753x; 1.0207x over previous
//
#include <hip/hip_runtime.h>

#define DD 64
#define BSH 8            // bucket = dst >> 8 (256 dsts per bucket)
#define NB_MAX 512       // supports n <= 131072
#define SCAP 4096        // staging slots per bucket (mean 3196, +16 sigma)
#define BIN_CH 4096      // edges per bin-kernel block

typedef __attribute__((ext_vector_type(8))) short bf16x8;
typedef __attribute__((ext_vector_type(4))) float f32x4;
union Frag { bf16x8 v; uint32_t d[4]; };

__device__ __forceinline__ float bf_lo(uint32_t d) { return __uint_as_float(d << 16); }
__device__ __forceinline__ float bf_hi(uint32_t d) { return __uint_as_float(d & 0xffff0000u); }
__device__ __forceinline__ float bf2f(uint32_t h) { return __uint_as_float(h << 16); }
__device__ __forceinline__ uint32_t f2bf(float f) {  // round-to-nearest-even
    uint32_t u = __float_as_uint(f);
    u += 0x7fffu + ((u >> 16) & 1u);
    return u >> 16;
}

// ====== K1: bin edges into dst-buckets (fixed-stride staging, LDS-aggregated) ======
__global__ __launch_bounds__(256) void bin_kernel(const int* __restrict__ src,
                                                  const int* __restrict__ dst,
                                                  int* __restrict__ bcnt,
                                                  uint32_t* __restrict__ staging,
                                                  int E, int NB) {
    __shared__ uint32_t cnt[NB_MAX];
    __shared__ uint32_t resv[NB_MAX];
    __shared__ uint16_t rk[BIN_CH];
    int tid = threadIdx.x;
    int base = blockIdx.x * BIN_CH;
    for (int b = tid; b < NB; b += 256) cnt[b] = 0;
    __syncthreads();
    for (int k = tid; k < BIN_CH; k += 256) {
        int g = base + k;
        if (g < E) {
            int b = dst[g] >> BSH;
            rk[k] = (uint16_t)atomicAdd(&cnt[b], 1u);
        }
    }
    __syncthreads();
    for (int b = tid; b < NB; b += 256) {
        uint32_t c = cnt[b];
        resv[b] = c ? (uint32_t)atomicAdd(&bcnt[b], (int)c) : 0u;
    }
    __syncthreads();
    for (int k = tid; k < BIN_CH; k += 256) {
        int g = base + k;
        if (g < E) {
            int s = src[g], d = dst[g];
            int b = d >> BSH;
            uint32_t pos = resv[b] + rk[k];
            if (pos < SCAP)  // statistically impossible overflow guard
                staging[(size_t)b * SCAP + pos] = ((uint32_t)s << BSH) | (uint32_t)(d & ((1 << BSH) - 1));
        }
    }
}

// ====== K3: per-bucket sort -> rowptr, inv, CSR srcs (coalesced out) ======
// srcs output is PRE-SHIFTED by 5 (dword offset of the 32-dword row).
__global__ __launch_bounds__(256) void sort_kernel(const int* __restrict__ bcnt,
                                                   const uint32_t* __restrict__ staging,
                                                   int* __restrict__ rowptr,
                                                   float* __restrict__ inv,
                                                   uint32_t* __restrict__ srcs,
                                                   int n, int E, int NB) {
    __shared__ uint32_t raw[SCAP];
    __shared__ uint32_t sorted[SCAP];
    __shared__ int scnt[1 << BSH];
    __shared__ int soff[1 << BSH];
    __shared__ int lcur[1 << BSH];
    __shared__ int red[256];
    int tid = threadIdx.x;
    int b = blockIdx.x;
    int base = b << BSH;
    int nd = min(1 << BSH, n - base);
    int cb = min(bcnt[b], SCAP);

    // bucket global base = prefix sum of bcnt[0..b)
    int part = 0;
    for (int j = tid; j < b; j += 256) part += bcnt[j];
    red[tid] = part;
    __syncthreads();
    for (int o = 128; o > 0; o >>= 1) {
        if (tid < o) red[tid] += red[tid + o];
        __syncthreads();
    }
    int bbase = red[0];

    // load records, histogram by local dst
    scnt[tid] = 0;
    __syncthreads();
    for (int k = tid; k < cb; k += 256) {
        uint32_t w = staging[(size_t)b * SCAP + k];
        raw[k] = w;
        atomicAdd(&scnt[w & ((1 << BSH) - 1)], 1);
    }
    __syncthreads();
    // exclusive scan of 256 counters (Hillis-Steele)
    int v = scnt[tid];
    red[tid] = v;
    __syncthreads();
    for (int o = 1; o < 256; o <<= 1) {
        int t = (tid >= o) ? red[tid - o] : 0;
        __syncthreads();
        red[tid] += t;
        __syncthreads();
    }
    soff[tid] = red[tid] - v;
    lcur[tid] = red[tid] - v;
    if (tid < nd) {
        rowptr[base + tid] = bbase + soff[tid];
        inv[base + tid] = rsqrtf((float)v + 1.0f);
    }
    if (b == NB - 1 && tid == 0) rowptr[n] = E;
    __syncthreads();
    // place into sorted order
    for (int k = tid; k < cb; k += 256) {
        uint32_t w = raw[k];
        int p = atomicAdd(&lcur[w & ((1 << BSH) - 1)], 1);
        sorted[p] = w >> BSH;
    }
    __syncthreads();
    for (int k = tid; k < cb; k += 256) srcs[bbase + k] = sorted[k] << 5;  // coalesced, pre-shifted
}

// ====== MFMA GEMM: [n,64] @ [64,64] -> bf16 rows PRE-SCALED by inv[row]. ======
// 16x16x32 bf16, split-bf16 = fp32-exact. Pre-scaling removes the per-edge
// inv[src] gather in agg: sum_j inv[s]*xw[s]*inv[i] = inv[i]*sum_j(inv[s]*xw[s]).
template <int XBF>
__global__ __launch_bounds__(256) void gemm64_mfma(const void* __restrict__ Xv,
                                                   const float* __restrict__ W,
                                                   const float* __restrict__ inv,
                                                   uint16_t* __restrict__ Y, int n) {
    __shared__ float Ws[DD * DD];
    int tid = threadIdx.x;
    for (int i = tid; i < DD * DD; i += 256) Ws[i] = W[i];
    __syncthreads();
    int lane = tid & 63, quad = lane >> 4, l16 = lane & 15;

    Frag bhi[4][2], blo[4][2];
#pragma unroll
    for (int t = 0; t < 4; ++t)
#pragma unroll
        for (int c = 0; c < 2; ++c) {
            int col = t * 16 + l16;
            int kb = c * 32 + quad * 8;
#pragma unroll
            for (int i = 0; i < 4; ++i) {
                float w0 = Ws[(kb + 2 * i) * DD + col];
                float w1 = Ws[(kb + 2 * i + 1) * DD + col];
                uint32_t h0 = f2bf(w0), h1 = f2bf(w1);
                uint32_t l0 = f2bf(w0 - bf2f(h0)), l1 = f2bf(w1 - bf2f(h1));
                bhi[t][c].d[i] = h0 | (h1 << 16);
                blo[t][c].d[i] = l0 | (l1 << 16);
            }
        }

    int ngroups = (n + 15) >> 4;
    int nwaves = gridDim.x * 4;
    int wid = blockIdx.x * 4 + (tid >> 6);
    for (int g = wid; g < ngroups; g += nwaves) {
        int rb = g << 4;
        int row = min(rb + l16, n - 1);
        f32x4 acc[4];
#pragma unroll
        for (int t = 0; t < 4; ++t) acc[t] = (f32x4){0.f, 0.f, 0.f, 0.f};
#pragma unroll
        for (int c = 0; c < 2; ++c) {
            Frag ahi, alo;
            if constexpr (XBF == 0) {
                const float* xr = (const float*)Xv + (size_t)row * DD + c * 32 + quad * 8;
                float4 x0 = *(const float4*)xr;
                float4 x1 = *(const float4*)(xr + 4);
                float f[8] = {x0.x, x0.y, x0.z, x0.w, x1.x, x1.y, x1.z, x1.w};
#pragma unroll
                for (int i = 0; i < 4; ++i) {
                    uint32_t h0 = f2bf(f[2 * i]), h1 = f2bf(f[2 * i + 1]);
                    ahi.d[i] = h0 | (h1 << 16);
                    alo.d[i] = f2bf(f[2 * i] - bf2f(h0)) | (f2bf(f[2 * i + 1] - bf2f(h1)) << 16);
                }
            } else {
                const int4* xr = (const int4*)((const uint32_t*)Xv + (size_t)row * 32 + c * 16 + quad * 4);
                int4 a = *xr;
                ahi.d[0] = a.x; ahi.d[1] = a.y; ahi.d[2] = a.z; ahi.d[3] = a.w;
            }
#pragma unroll
            for (int t = 0; t < 4; ++t) {
                acc[t] = __builtin_amdgcn_mfma_f32_16x16x32_bf16(ahi.v, bhi[t][c].v, acc[t], 0, 0, 0);
                acc[t] = __builtin_amdgcn_mfma_f32_16x16x32_bf16(ahi.v, blo[t][c].v, acc[t], 0, 0, 0);
                if constexpr (XBF == 0)
                    acc[t] = __builtin_amdgcn_mfma_f32_16x16x32_bf16(alo.v, bhi[t][c].v, acc[t], 0, 0, 0);
            }
        }
#pragma unroll
        for (int r = 0; r < 4; ++r) {
            int ro = rb + quad * 4 + r;
            if (ro < n) {
                float sc = inv[ro];
#pragma unroll
                for (int t = 0; t < 4; ++t)
                    Y[(size_t)ro * DD + t * 16 + l16] = (uint16_t)f2bf(acc[t][r] * sc);
            }
        }
    }
}

// ====== fused aggregation: TWO nodes per wave (32 lanes each), 4 edge-streams/node ======
// Half h (lanes h*32..h*32+31) owns node 2w+h. Group g (8 lanes) owns edge stream
// jstart+g, +4, ...; lane m loads row dwords 4m..4m+3 (16 B). Rows pre-scaled by
// inv[src]; whole sum (incl. self row) scaled by inv[dst] once at the end.
// src prefetch 4 ahead; row prefetch 3 ahead -> ~all gathers issue from prologue
// (avg trips = deg/4 ~ 3.1). One instruction stream covers both nodes: prologue/
// reduction/epilogue cost per node is halved vs 1-node-per-wave.
template <int MODE>
__global__ __launch_bounds__(256) void agg_kernel(const int* __restrict__ rowptr,
                                                  const uint32_t* __restrict__ srcs,  // pre-shifted <<5
                                                  const float* __restrict__ inv,
                                                  const uint32_t* __restrict__ XWb,  // [n][32] dwords
                                                  const float* __restrict__ b,
                                                  void* __restrict__ OUTv, int n) {
    int gid = blockIdx.x * 256 + threadIdx.x;
    int w = gid >> 6, lane = gid & 63;
    if (w * 2 >= n) return;
    int h = lane >> 5, l = lane & 31;
    int i = w * 2 + h;
    bool act = i < n;
    int ic = act ? i : n - 1;
    int g = l >> 3, m = l & 7;

    float a[8];
#pragma unroll
    for (int k = 0; k < 8; ++k) a[k] = 0.f;
    if (g == 0) {  // self-loop: row ic is pre-scaled by inv[ic]; final *iv gives inv^2
        int4 d = *(const int4*)(XWb + (size_t)ic * 32 + 4 * m);
        a[0] = bf_lo((uint32_t)d.x); a[1] = bf_hi((uint32_t)d.x);
        a[2] = bf_lo((uint32_t)d.y); a[3] = bf_hi((uint32_t)d.y);
        a[4] = bf_lo((uint32_t)d.z); a[5] = bf_hi((uint32_t)d.z);
        a[6] = bf_lo((uint32_t)d.w); a[7] = bf_hi((uint32_t)d.w);
    }

    int jstart = rowptr[ic];
    int jend = act ? rowptr[ic + 1] : jstart;
    if (jstart < jend) {
        int last = jend - 1;
        int jq = jstart + g;  // this group's stream: jq, jq+4, ...
        uint32_t s0 = srcs[min(jq, last)];
        uint32_t s1 = srcs[min(jq + 4, last)];
        uint32_t s2 = srcs[min(jq + 8, last)];
        uint32_t s3 = srcs[min(jq + 12, last)];
        int4 d0 = *(const int4*)(XWb + s0 + 4 * m);
        int4 d1 = *(const int4*)(XWb + s1 + 4 * m);
        int4 d2 = *(const int4*)(XWb + s2 + 4 * m);
        for (int j = jq; j < jend; j += 4) {
            uint32_t s4 = srcs[min(j + 16, last)];            // src prefetch (4 ahead)
            int4 d3 = *(const int4*)(XWb + s3 + 4 * m);       // row prefetch (3 ahead)
            a[0] += bf_lo((uint32_t)d0.x); a[1] += bf_hi((uint32_t)d0.x);
            a[2] += bf_lo((uint32_t)d0.y); a[3] += bf_hi((uint32_t)d0.y);
            a[4] += bf_lo((uint32_t)d0.z); a[5] += bf_hi((uint32_t)d0.z);
            a[6] += bf_lo((uint32_t)d0.w); a[7] += bf_hi((uint32_t)d0.w);
            s3 = s4;
            d0 = d1; d1 = d2; d2 = d3;
        }
    }

    // combine 4 groups within each half: lanes {l, l^8, l^16} (all intra-half)
#pragma unroll
    for (int k = 0; k < 8; ++k) {
        a[k] += __shfl_xor(a[k], 8, 64);
        a[k] += __shfl_xor(a[k], 16, 64);
    }

    float iv = inv[ic];  // half-uniform
    float4 bb0 = *(const float4*)(b + 8 * m);
    float4 bb1 = *(const float4*)(b + 8 * m + 4);
    float f0 = fmaf(a[0], iv, bb0.x), f1 = fmaf(a[1], iv, bb0.y);
    float f2 = fmaf(a[2], iv, bb0.z), f3 = fmaf(a[3], iv, bb0.w);
    float f4 = fmaf(a[4], iv, bb1.x), f5 = fmaf(a[5], iv, bb1.y);
    float f6 = fmaf(a[6], iv, bb1.z), f7 = fmaf(a[7], iv, bb1.w);

    if (MODE == 0) {
        if (act && g == 0) {
            int4 d;
            d.x = (int)((f2bf(fmaxf(f1, 0.f)) << 16) | f2bf(fmaxf(f0, 0.f)));
            d.y = (int)((f2bf(fmaxf(f3, 0.f)) << 16) | f2bf(fmaxf(f2, 0.f)));
            d.z = (int)((f2bf(fmaxf(f5, 0.f)) << 16) | f2bf(fmaxf(f4, 0.f)));
            d.w = (int)((f2bf(fmaxf(f7, 0.f)) << 16) | f2bf(fmaxf(f6, 0.f)));
            *(int4*)((uint32_t*)OUTv + (size_t)i * 32 + 4 * m) = d;
        }
    } else {
        // cross-feature reduce over m (lanes l^4, l^2, l^1 — intra-half)
        float mx = fmaxf(fmaxf(fmaxf(f0, f1), fmaxf(f2, f3)),
                         fmaxf(fmaxf(f4, f5), fmaxf(f6, f7)));
#pragma unroll
        for (int o = 4; o > 0; o >>= 1) mx = fmaxf(mx, __shfl_xor(mx, o, 64));
        float e = __expf(f0 - mx) + __expf(f1 - mx) + __expf(f2 - mx) + __expf(f3 - mx)
                + __expf(f4 - mx) + __expf(f5 - mx) + __expf(f6 - mx) + __expf(f7 - mx);
#pragma unroll
        for (int o = 4; o > 0; o >>= 1) e += __shfl_xor(e, o, 64);
        float ls = __logf(e);
        if (act && g == 0) {
            float4 r0 = make_float4(f0 - mx - ls, f1 - mx - ls, f2 - mx - ls, f3 - mx - ls);
            float4 r1 = make_float4(f4 - mx - ls, f5 - mx - ls, f6 - mx - ls, f7 - mx - ls);
            *(float4*)((float*)OUTv + (size_t)i * DD + 8 * m) = r0;
            *(float4*)((float*)OUTv + (size_t)i * DD + 8 * m + 4) = r1;
        }
    }
}

extern "C" void kernel_launch(void* const* d_in, const int* in_sizes, int n_in,
                              void* d_out, int out_size, void* d_ws, size_t ws_size,
                              hipStream_t stream) {
    const float* x  = (const float*)d_in[0];
    const int*   ei = (const int*)d_in[1];
    const float* W1 = (const float*)d_in[2];
    const float* b1 = (const float*)d_in[3];
    const float* W2 = (const float*)d_in[4];
    const float* b2 = (const float*)d_in[5];
    float* out = (float*)d_out;

    const int n = in_sizes[0] / DD;
    const int E = in_sizes[1] / 2;
    const int* src = ei;
    const int* dst = ei + E;
    const int NB = (n + (1 << BSH) - 1) >> BSH;  // 391 for n=100k

    // workspace layout (int units)
    size_t off = 0;
    int* base = (int*)d_ws;
    int* bcnt = base + off; off += NB_MAX;
    uint32_t* staging = (uint32_t*)(base + off); off += (size_t)NB_MAX * SCAP;
    uint32_t* srcs = (uint32_t*)(base + off); off += E;
    int* rowptr = base + off; off += (size_t)n + 1;
    float* inv  = (float*)(base + off); off += n;
    uint32_t* XWb = (uint32_t*)(base + off); off += (size_t)n * 32;  // bf16 [n][64]
    uint32_t* hb  = (uint32_t*)(base + off); off += (size_t)n * 32;  // bf16 [n][64]

    hipMemsetAsync(bcnt, 0, NB_MAX * sizeof(int), stream);
    bin_kernel<<<(E + BIN_CH - 1) / BIN_CH, 256, 0, stream>>>(src, dst, bcnt, staging, E, NB);
    sort_kernel<<<NB, 256, 0, stream>>>(bcnt, staging, rowptr, inv, srcs, n, E, NB);

    // gemm grid: exactly one 16-row group per wave (4 waves/block)
    const int ngroups = (n + 15) >> 4;
    const int gblocks = (ngroups + 3) / 4;
    // agg grid: two nodes per wave (4 waves/block)
    const int ablocks = (n + 7) / 8;

    // layer 1 (gemm pre-scales rows by inv[row]; needs sort_kernel's inv -> same stream, ordered)
    gemm64_mfma<0><<<gblocks, 256, 0, stream>>>(x, W1, inv, (uint16_t*)XWb, n);
    agg_kernel<0><<<ablocks, 256, 0, stream>>>(rowptr, srcs, inv, XWb, b1, hb, n);

    // layer 2
    gemm64_mfma<1><<<gblocks, 256, 0, stream>>>(hb, W2, inv, (uint16_t*)XWb, n);
    agg_kernel<1><<<ablocks, 256, 0, stream>>>(rowptr, srcs, inv, XWb, b2, out, n);
}